// Round 1
// baseline (654.931 us; speedup 1.0000x reference)
//
#include <hip/hip_runtime.h>

// Problem constants (fixed by the reference)
#define T_SEQ   4096
#define BATCH   32
#define DIM     512
#define MROWS   (T_SEQ * BATCH)          // 131072 GEMM rows
#define S_STRIDE (BATCH * DIM)           // 16384 floats per time step
#define OUT_ELEMS ((size_t)T_SEQ * BATCH * DIM)   // 67108864

typedef __bf16 bf8_t __attribute__((ext_vector_type(8)));    // 8 bf16 = 4 VGPRs
typedef float  f4_t  __attribute__((ext_vector_type(4)));
typedef unsigned short u16x8 __attribute__((ext_vector_type(8)));
typedef __attribute__((address_space(1))) void gvoid_t;
typedef __attribute__((address_space(3))) void lvoid_t;

__device__ __forceinline__ unsigned short f2bf(float f) {
    unsigned int u = __float_as_uint(f);
    u += 0x7FFFu + ((u >> 16) & 1u);     // round-to-nearest-even
    return (unsigned short)(u >> 16);
}

// ---------------- f32 -> bf16 convert, 8 elems/thread ----------------
__global__ __launch_bounds__(256) void k_cvt(const float* __restrict__ in,
                                             unsigned short* __restrict__ out) {
    size_t i = ((size_t)blockIdx.x * 256 + threadIdx.x) * 8;
    float4 a = *reinterpret_cast<const float4*>(in + i);
    float4 b = *reinterpret_cast<const float4*>(in + i + 4);
    u16x8 o;
    o[0] = f2bf(a.x); o[1] = f2bf(a.y); o[2] = f2bf(a.z); o[3] = f2bf(a.w);
    o[4] = f2bf(b.x); o[5] = f2bf(b.y); o[6] = f2bf(b.z); o[7] = f2bf(b.w);
    *reinterpret_cast<u16x8*>(out + i) = o;
}

// ---------------- bf16 GEMM  C[M,512] = A[M,512] * B[512,512]^T ------
// m97 structure: 128x128 tile, BK=32, 4 waves (2x2), 4x4 16x16x32 MFMA per wave,
// global_load_lds width=16 staging, 2 barriers per K-step.
__global__ __launch_bounds__(256)
void k_gemm_bt(const unsigned short* __restrict__ A,   // M x 512 bf16 bits
               const unsigned short* __restrict__ B,   // 512 x 512 bf16 bits (N-major, K contiguous)
               float* __restrict__ C) {                // M x 512 f32
    __shared__ unsigned short As[128 * 32];
    __shared__ unsigned short Bs[128 * 32];

    const int tid  = threadIdx.x;
    const int lane = tid & 63;
    const int wv   = tid >> 6;          // wave 0..3
    const int wr   = wv >> 1;           // wave row (0..1) -> 64 rows
    const int wc   = wv & 1;            // wave col (0..1) -> 64 cols
    const size_t gm = (size_t)blockIdx.x * 128;
    const int    gn = blockIdx.y * 128;

    // staging map: thread -> (row = i*64 + tid/4, k-seg = (tid%4)*8); lane-linear in LDS
    const int srow = tid >> 2;          // 0..63
    const int skk  = (tid & 3) * 8;     // 0,8,16,24

    f4_t acc[4][4] = {};                // zero-init accumulators

    const int l15 = lane & 15;
    const int lk  = (lane >> 4) * 8;    // k offset within BK for fragments

    for (int k0 = 0; k0 < 512; k0 += 32) {
        // ---- stage A,B tiles: 4 x global_load_lds_dwordx4 per thread-group ----
#pragma unroll
        for (int i = 0; i < 2; ++i) {
            const unsigned short* ga = A + (gm + (size_t)(i * 64 + srow)) * 512 + k0 + skk;
            const unsigned short* gb = B + (size_t)(gn + i * 64 + srow) * 512 + k0 + skk;
            __builtin_amdgcn_global_load_lds((gvoid_t*)ga, (lvoid_t*)&As[i * 2048 + wv * 512], 16, 0, 0);
            __builtin_amdgcn_global_load_lds((gvoid_t*)gb, (lvoid_t*)&Bs[i * 2048 + wv * 512], 16, 0, 0);
        }
        __syncthreads();   // drains vmcnt; staged tile visible

        bf8_t af[4], bfz[4];
#pragma unroll
        for (int m = 0; m < 4; ++m)
            af[m] = *reinterpret_cast<const bf8_t*>(&As[(wr * 64 + m * 16 + l15) * 32 + lk]);
#pragma unroll
        for (int n = 0; n < 4; ++n)
            bfz[n] = *reinterpret_cast<const bf8_t*>(&Bs[(wc * 64 + n * 16 + l15) * 32 + lk]);
#pragma unroll
        for (int m = 0; m < 4; ++m)
#pragma unroll
            for (int n = 0; n < 4; ++n)
                acc[m][n] = __builtin_amdgcn_mfma_f32_16x16x32_bf16(af[m], bfz[n], acc[m][n], 0, 0, 0);
        __syncthreads();   // all LDS reads done before next stage overwrites
    }

    // C/D layout (HW-verified): col = lane&15, row = (lane>>4)*4 + reg
    const int crow0 = (lane >> 4) * 4;
#pragma unroll
    for (int m = 0; m < 4; ++m)
#pragma unroll
        for (int n = 0; n < 4; ++n) {
            const size_t row0 = gm + (size_t)(wr * 64 + m * 16 + crow0);
            const int    col  = gn + wc * 64 + n * 16 + l15;
#pragma unroll
            for (int r = 0; r < 4; ++r)
                C[(row0 + r) * 512 + col] = acc[m][n][r];
        }
}

// ---------------- sequential ReLU scan over T ------------------------
// One thread per (b,h) chain; 4-stage x 16-deep register pipeline (static idx).
// MODE 0: write f32 (may alias proj: per-thread read-before-write, same index set)
// MODE 1: write bf16 (feeds next layer's GEMM)
template <int MODE>
__global__ __launch_bounds__(64)
void k_scan(const float* __restrict__ proj,
            const float* __restrict__ w_hh,
            const float* __restrict__ b_ih,
            float* __restrict__ of32,
            unsigned short* __restrict__ ob16,
            float* __restrict__ hT) {
    const int gid = blockIdx.x * 64 + threadIdx.x;    // 0..16383 = b*512 + h
    const float w  = w_hh[gid & 511];
    const float bs = b_ih[gid & 511];
    const float* p = proj + gid;

    float st[4][16];
    float hv = 0.f;

#pragma unroll
    for (int g = 0; g < 4; ++g)
#pragma unroll
        for (int j = 0; j < 16; ++j)
            st[g][j] = p[(g * 16 + j) * S_STRIDE];

    for (int t0 = 0; t0 < T_SEQ; t0 += 64) {
#pragma unroll
        for (int g = 0; g < 4; ++g) {
            // consume group g
#pragma unroll
            for (int j = 0; j < 16; ++j) {
                hv = fmaxf(fmaf(w, hv, st[g][j] + bs), 0.f);
                const int t = t0 + g * 16 + j;
                if (MODE == 0) of32[(size_t)t * S_STRIDE + gid] = hv;
                else           ob16[(size_t)t * S_STRIDE + gid] = f2bf(hv);
            }
            // refill group g for t0+64 (keeps ~48-64 loads in flight)
            const int tn = t0 + 64 + g * 16;
            if (tn < T_SEQ) {
#pragma unroll
                for (int j = 0; j < 16; ++j)
                    st[g][j] = p[(tn + j) * S_STRIDE];
            }
        }
    }
    hT[gid] = hv;
}

extern "C" void kernel_launch(void* const* d_in, const int* in_sizes, int n_in,
                              void* d_out, int out_size, void* d_ws, size_t ws_size,
                              hipStream_t stream) {
    const float* x    = (const float*)d_in[0];   // (4096,32,512)
    const float* W_ih = (const float*)d_in[1];   // (2,512,512)
    const float* w_hh = (const float*)d_in[2];   // (2,512)
    const float* b_ih = (const float*)d_in[3];   // (2,512)
    float* out = (float*)d_out;

    // workspace layout: [xb/ys1 bf16: 134,217,728 B][Wb bf16: 1,048,576 B]
    unsigned short* xb = (unsigned short*)d_ws;
    unsigned short* Wb = (unsigned short*)((char*)d_ws + OUT_ELEMS * 2);

    float* proj = out;              // proj lives in d_out's out region (exact fit)
    float* hT   = out + OUT_ELEMS;  // h_n tail: (2,32,512)

    dim3 ggrid(MROWS / 128, DIM / 128);

    // 1. x -> bf16
    k_cvt<<<(int)(OUT_ELEMS / 8 / 256), 256, 0, stream>>>(x, xb);
    // 2. W -> bf16 (2*512*512 = 524288)
    k_cvt<<<524288 / 8 / 256, 256, 0, stream>>>(W_ih, Wb);
    // 3. layer-0 GEMM: proj1 = x @ W0^T   (into d_out)
    k_gemm_bt<<<ggrid, 256, 0, stream>>>(xb, Wb, proj);
    // 4. layer-0 scan: ys1 (bf16, overwrites xb) + hT0
    k_scan<1><<<256, 64, 0, stream>>>(proj, w_hh, b_ih, nullptr, xb, hT);
    // 5. layer-1 GEMM: proj2 = ys1 @ W1^T (overwrites proj1 in d_out)
    k_gemm_bt<<<ggrid, 256, 0, stream>>>(xb, Wb + 512 * 512, proj);
    // 6. layer-1 scan: final out (f32, in-place in d_out) + hT1
    k_scan<0><<<256, 64, 0, stream>>>(proj, w_hh + DIM, b_ih + DIM, out, nullptr, hT + S_STRIDE);
}

// Round 2
// 512.157 us; speedup vs baseline: 1.2788x; 1.2788x over previous
//
#include <hip/hip_runtime.h>

// Problem constants (fixed by the reference)
#define T_SEQ   4096
#define BATCH   32
#define DIM     512
#define MROWS   (T_SEQ * BATCH)          // 131072 GEMM rows
#define S_STRIDE (BATCH * DIM)           // 16384 elements per time step
#define OUT_ELEMS ((size_t)T_SEQ * BATCH * DIM)   // 67108864
#define NCH     32                        // T-chunks for parallel scan
#define CLEN    (T_SEQ / NCH)             // 128 steps per chunk
#define NCHAIN  (BATCH * DIM)             // 16384 independent chains

typedef __bf16 bf8_t __attribute__((ext_vector_type(8)));    // 8 bf16 = 4 VGPRs
typedef float  f4_t  __attribute__((ext_vector_type(4)));
typedef unsigned short u16x8 __attribute__((ext_vector_type(8)));
typedef __attribute__((address_space(1))) void gvoid_t;
typedef __attribute__((address_space(3))) void lvoid_t;

__device__ __forceinline__ unsigned short f2bf(float f) {
    unsigned int u = __float_as_uint(f);
    u += 0x7FFFu + ((u >> 16) & 1u);     // round-to-nearest-even
    return (unsigned short)(u >> 16);
}
__device__ __forceinline__ float bf2f(unsigned short b) {
    return __uint_as_float(((unsigned int)b) << 16);
}

// ---------------- f32 -> bf16 convert, 8 elems/thread ----------------
__global__ __launch_bounds__(256) void k_cvt(const float* __restrict__ in,
                                             unsigned short* __restrict__ out) {
    size_t i = ((size_t)blockIdx.x * 256 + threadIdx.x) * 8;
    float4 a = *reinterpret_cast<const float4*>(in + i);
    float4 b = *reinterpret_cast<const float4*>(in + i + 4);
    u16x8 o;
    o[0] = f2bf(a.x); o[1] = f2bf(a.y); o[2] = f2bf(a.z); o[3] = f2bf(a.w);
    o[4] = f2bf(b.x); o[5] = f2bf(b.y); o[6] = f2bf(b.z); o[7] = f2bf(b.w);
    *reinterpret_cast<u16x8*>(out + i) = o;
}

// ---------------- bf16 GEMM  C[M,512] = A[M,512] * B[512,512]^T ------
// m97 structure; grid = (N-tiles, M-tiles) so the 4 co-resident blocks per
// A-panel (same blockIdx.y) hit L2 on A. C written as bf16 (halves write BW).
__global__ __launch_bounds__(256)
void k_gemm_bt(const unsigned short* __restrict__ A,   // M x 512 bf16 bits
               const unsigned short* __restrict__ B,   // 512 x 512 bf16 bits
               unsigned short* __restrict__ C) {       // M x 512 bf16
    __shared__ unsigned short As[128 * 32];
    __shared__ unsigned short Bs[128 * 32];

    const int tid  = threadIdx.x;
    const int lane = tid & 63;
    const int wv   = tid >> 6;
    const int wr   = wv >> 1;
    const int wc   = wv & 1;
    const size_t gm = (size_t)blockIdx.y * 128;   // M-tile
    const int    gn = blockIdx.x * 128;           // N-tile

    const int srow = tid >> 2;
    const int skk  = (tid & 3) * 8;

    f4_t acc[4][4] = {};

    const int l15 = lane & 15;
    const int lk  = (lane >> 4) * 8;

    for (int k0 = 0; k0 < 512; k0 += 32) {
#pragma unroll
        for (int i = 0; i < 2; ++i) {
            const unsigned short* ga = A + (gm + (size_t)(i * 64 + srow)) * 512 + k0 + skk;
            const unsigned short* gb = B + (size_t)(gn + i * 64 + srow) * 512 + k0 + skk;
            __builtin_amdgcn_global_load_lds((gvoid_t*)ga, (lvoid_t*)&As[i * 2048 + wv * 512], 16, 0, 0);
            __builtin_amdgcn_global_load_lds((gvoid_t*)gb, (lvoid_t*)&Bs[i * 2048 + wv * 512], 16, 0, 0);
        }
        __syncthreads();

        bf8_t af[4], bfz[4];
#pragma unroll
        for (int m = 0; m < 4; ++m)
            af[m] = *reinterpret_cast<const bf8_t*>(&As[(wr * 64 + m * 16 + l15) * 32 + lk]);
#pragma unroll
        for (int n = 0; n < 4; ++n)
            bfz[n] = *reinterpret_cast<const bf8_t*>(&Bs[(wc * 64 + n * 16 + l15) * 32 + lk]);
#pragma unroll
        for (int m = 0; m < 4; ++m)
#pragma unroll
            for (int n = 0; n < 4; ++n)
                acc[m][n] = __builtin_amdgcn_mfma_f32_16x16x32_bf16(af[m], bfz[n], acc[m][n], 0, 0, 0);
        __syncthreads();
    }

    const int crow0 = (lane >> 4) * 4;
#pragma unroll
    for (int m = 0; m < 4; ++m)
#pragma unroll
        for (int n = 0; n < 4; ++n) {
            const size_t row0 = gm + (size_t)(wr * 64 + m * 16 + crow0);
            const int    col  = gn + wc * 64 + n * 16 + l15;
#pragma unroll
            for (int r = 0; r < 4; ++r)
                C[(row0 + r) * 512 + col] = f2bf(acc[m][n][r]);
        }
}

// ------------- chunk-parallel scan, pass 1: per-chunk (A,B) summaries -------
// f_chunk(H) = max(A, B + w^CLEN * H)  for H >= 0.
// A' = max(0, q + w*A) (plain run from 0), B' = q + w*B.
__global__ __launch_bounds__(256)
void k_scan_p1(const unsigned short* __restrict__ q,   // [T][16384] bf16
               const float* __restrict__ w_hh,         // 512 (layer slice)
               const float* __restrict__ b_ih,
               float* __restrict__ Asum,               // [NCH][16384]
               float* __restrict__ Bsum) {
    const int g = (blockIdx.x & 63) * 256 + threadIdx.x;  // chain id
    const int c = blockIdx.x >> 6;                        // chunk id
    const float w  = w_hh[g & 511];
    const float bs = b_ih[g & 511];
    const unsigned short* p = q + (size_t)c * CLEN * S_STRIDE + g;

    float A = 0.f, Bv = 0.f;
    float s0[8], s1[8];
#pragma unroll
    for (int j = 0; j < 8; ++j) s0[j] = bf2f(p[(size_t)j * S_STRIDE]);
#pragma unroll
    for (int j = 0; j < 8; ++j) s1[j] = bf2f(p[(size_t)(8 + j) * S_STRIDE]);

    for (int j0 = 0; j0 < CLEN; j0 += 16) {
#pragma unroll
        for (int j = 0; j < 8; ++j) {
            float qv = s0[j] + bs;
            A  = fmaxf(fmaf(w, A, qv), 0.f);
            Bv = fmaf(w, Bv, qv);
        }
        if (j0 + 16 < CLEN) {
#pragma unroll
            for (int j = 0; j < 8; ++j) s0[j] = bf2f(p[(size_t)(j0 + 16 + j) * S_STRIDE]);
        }
#pragma unroll
        for (int j = 0; j < 8; ++j) {
            float qv = s1[j] + bs;
            A  = fmaxf(fmaf(w, A, qv), 0.f);
            Bv = fmaf(w, Bv, qv);
        }
        if (j0 + 24 < CLEN) {
#pragma unroll
            for (int j = 0; j < 8; ++j) s1[j] = bf2f(p[(size_t)(j0 + 24 + j) * S_STRIDE]);
        }
    }
    Asum[(size_t)c * NCHAIN + g] = A;
    Bsum[(size_t)c * NCHAIN + g] = Bv;
}

// ------------- stitch: sequential over NCH chunk summaries -----------------
__global__ __launch_bounds__(256)
void k_stitch(const float* __restrict__ Asum, const float* __restrict__ Bsum,
              const float* __restrict__ w_hh,
              float* __restrict__ Hin,      // [NCH][16384] chunk entry states
              float* __restrict__ hT) {     // [16384] final hidden
    const int g = blockIdx.x * 256 + threadIdx.x;
    const float w = w_hh[g & 511];
    float cw = w;                            // w^CLEN, CLEN = 2^7
#pragma unroll
    for (int i = 0; i < 7; ++i) cw *= cw;

    float a[NCH], b[NCH];
#pragma unroll
    for (int c = 0; c < NCH; ++c) {
        a[c] = Asum[(size_t)c * NCHAIN + g];
        b[c] = Bsum[(size_t)c * NCHAIN + g];
    }
    float H = 0.f;
#pragma unroll
    for (int c = 0; c < NCH; ++c) {
        Hin[(size_t)c * NCHAIN + g] = H;
        H = fmaxf(a[c], fmaf(cw, H, b[c]));
    }
    hT[g] = H;
}

// ------------- pass 2: exact replay within each chunk given H_in ------------
// MODE 0: write f32 out; MODE 1: write bf16 (feeds next layer's GEMM)
template <int MODE>
__global__ __launch_bounds__(256)
void k_scan_p2(const unsigned short* __restrict__ q,
               const float* __restrict__ w_hh,
               const float* __restrict__ b_ih,
               const float* __restrict__ Hin,
               float* __restrict__ of32,
               unsigned short* __restrict__ ob16) {
    const int g = (blockIdx.x & 63) * 256 + threadIdx.x;
    const int c = blockIdx.x >> 6;
    const float w  = w_hh[g & 511];
    const float bs = b_ih[g & 511];
    const size_t base = (size_t)c * CLEN * S_STRIDE + g;
    const unsigned short* p = q + base;

    float h = Hin[(size_t)c * NCHAIN + g];

    float s0[8], s1[8];
#pragma unroll
    for (int j = 0; j < 8; ++j) s0[j] = bf2f(p[(size_t)j * S_STRIDE]);
#pragma unroll
    for (int j = 0; j < 8; ++j) s1[j] = bf2f(p[(size_t)(8 + j) * S_STRIDE]);

    for (int j0 = 0; j0 < CLEN; j0 += 16) {
#pragma unroll
        for (int j = 0; j < 8; ++j) {
            h = fmaxf(fmaf(w, h, s0[j] + bs), 0.f);
            const size_t idx = base + (size_t)(j0 + j) * S_STRIDE;
            if (MODE == 0) of32[idx] = h; else ob16[idx] = f2bf(h);
        }
        if (j0 + 16 < CLEN) {
#pragma unroll
            for (int j = 0; j < 8; ++j) s0[j] = bf2f(p[(size_t)(j0 + 16 + j) * S_STRIDE]);
        }
#pragma unroll
        for (int j = 0; j < 8; ++j) {
            h = fmaxf(fmaf(w, h, s1[j] + bs), 0.f);
            const size_t idx = base + (size_t)(j0 + 8 + j) * S_STRIDE;
            if (MODE == 0) of32[idx] = h; else ob16[idx] = f2bf(h);
        }
        if (j0 + 24 < CLEN) {
#pragma unroll
            for (int j = 0; j < 8; ++j) s1[j] = bf2f(p[(size_t)(j0 + 24 + j) * S_STRIDE]);
        }
    }
}

extern "C" void kernel_launch(void* const* d_in, const int* in_sizes, int n_in,
                              void* d_out, int out_size, void* d_ws, size_t ws_size,
                              hipStream_t stream) {
    const float* x    = (const float*)d_in[0];   // (4096,32,512)
    const float* W_ih = (const float*)d_in[1];   // (2,512,512)
    const float* w_hh = (const float*)d_in[2];   // (2,512)
    const float* b_ih = (const float*)d_in[3];   // (2,512)

    // ---- workspace layout (~142 MB) ----
    unsigned short* xb  = (unsigned short*)d_ws;                  // 134 MB; reused as proj2
    unsigned short* Wb  = xb + OUT_ELEMS;                         // 1 MB
    float* Asum = (float*)(Wb + 2 * 512 * 512);                   // 2 MB
    float* Bsum = Asum + (size_t)NCH * NCHAIN;                    // 2 MB
    float* Hin  = Bsum + (size_t)NCH * NCHAIN;                    // 2 MB

    // ---- d_out staging: proj1 in lower half (bf16), ys1 in upper half ----
    unsigned short* proj1 = (unsigned short*)d_out;               // bytes [0, 134M)
    unsigned short* ys1   = proj1 + OUT_ELEMS;                    // bytes [134M, 268M)
    unsigned short* proj2 = xb;                                   // reuse (xb dead after gemm1)
    float* out = (float*)d_out;
    float* hT  = out + OUT_ELEMS;                                 // h_n (2,32,512)

    dim3 ggrid(DIM / 128, MROWS / 128);     // (4, 1024): A-panel reuse in L2
    const int sgrid = 64 * NCH;             // 2048 blocks for scan passes

    // 1-2. casts
    k_cvt<<<(int)(OUT_ELEMS / 8 / 256), 256, 0, stream>>>(x, xb);
    k_cvt<<<524288 / 8 / 256, 256, 0, stream>>>(W_ih, Wb);
    // 3. layer-0 GEMM -> proj1 (bf16, d_out lower half)
    k_gemm_bt<<<ggrid, 256, 0, stream>>>(xb, Wb, proj1);
    // 4-6. layer-0 chunked scan -> ys1 (bf16, d_out upper half) + hT0
    k_scan_p1<<<sgrid, 256, 0, stream>>>(proj1, w_hh, b_ih, Asum, Bsum);
    k_stitch<<<NCHAIN / 256, 256, 0, stream>>>(Asum, Bsum, w_hh, Hin, hT);
    k_scan_p2<1><<<sgrid, 256, 0, stream>>>(proj1, w_hh, b_ih, Hin, nullptr, ys1);
    // 7. layer-1 GEMM -> proj2 (bf16, ws; overwrites xb which is dead)
    k_gemm_bt<<<ggrid, 256, 0, stream>>>(ys1, Wb + 512 * 512, proj2);
    // 8-10. layer-1 chunked scan -> final out (f32, overwrites proj1/ys1) + hT1
    k_scan_p1<<<sgrid, 256, 0, stream>>>(proj2, w_hh + DIM, b_ih + DIM, Asum, Bsum);
    k_stitch<<<NCHAIN / 256, 256, 0, stream>>>(Asum, Bsum, w_hh + DIM, Hin, hT + NCHAIN);
    k_scan_p2<0><<<sgrid, 256, 0, stream>>>(proj2, w_hh + DIM, b_ih + DIM, Hin, out, nullptr);
}

// Round 3
// 469.095 us; speedup vs baseline: 1.3962x; 1.0918x over previous
//
#include <hip/hip_runtime.h>

// Problem constants (fixed by the reference)
#define T_SEQ   4096
#define BATCH   32
#define DIM     512
#define MROWS   (T_SEQ * BATCH)          // 131072 GEMM rows
#define S_STRIDE (BATCH * DIM)           // 16384 elements per time step
#define OUT_ELEMS ((size_t)T_SEQ * BATCH * DIM)   // 67108864
#define NCH     32                        // T-chunks for parallel scan
#define CLEN    (T_SEQ / NCH)             // 128 steps per chunk
#define NCHAIN  (BATCH * DIM)             // 16384 independent chains
#define NWG     ((MROWS / 128) * (DIM / 128))     // 4096 GEMM workgroups

typedef __bf16 bf8_t __attribute__((ext_vector_type(8)));    // 8 bf16 = 4 VGPRs
typedef float  f4_t  __attribute__((ext_vector_type(4)));
typedef unsigned short u16x8 __attribute__((ext_vector_type(8)));
typedef __attribute__((address_space(1))) void gvoid_t;
typedef __attribute__((address_space(3))) void lvoid_t;

__device__ __forceinline__ unsigned short f2bf(float f) {
    unsigned int u = __float_as_uint(f);
    u += 0x7FFFu + ((u >> 16) & 1u);     // round-to-nearest-even
    return (unsigned short)(u >> 16);
}
__device__ __forceinline__ float bf2f(unsigned short b) {
    return __uint_as_float(((unsigned int)b) << 16);
}

// ---------------- f32 -> bf16 convert (weights only now) -------------
__global__ __launch_bounds__(256) void k_cvt(const float* __restrict__ in,
                                             unsigned short* __restrict__ out) {
    size_t i = ((size_t)blockIdx.x * 256 + threadIdx.x) * 8;
    float4 a = *reinterpret_cast<const float4*>(in + i);
    float4 b = *reinterpret_cast<const float4*>(in + i + 4);
    u16x8 o;
    o[0] = f2bf(a.x); o[1] = f2bf(a.y); o[2] = f2bf(a.z); o[3] = f2bf(a.w);
    o[4] = f2bf(b.x); o[5] = f2bf(b.y); o[6] = f2bf(b.z); o[7] = f2bf(b.w);
    *reinterpret_cast<u16x8*>(out + i) = o;
}

// ---------------- bf16 GEMM  C[M,512] = A[M,512] * B[512,512]^T ------
// m97 structure, 128x128 tile, BK=32.
// AF32=1: A is f32, converted to bf16 during reg-staged LDS writes
//         (lane map tid*8 == (tid>>2)*32 + (tid&3)*8, identical layout
//          to the global_load_lds path).
// XCD-chunked swizzle: the 4 N-tiles sharing an A-panel stay on one XCD.
template <int AF32>
__global__ __launch_bounds__(256)
void k_gemm_bt(const void* __restrict__ Ap,
               const unsigned short* __restrict__ B,
               unsigned short* __restrict__ C) {
    __shared__ unsigned short As[128 * 32];
    __shared__ unsigned short Bs[128 * 32];

    const int tid  = threadIdx.x;
    const int lane = tid & 63;
    const int wv   = tid >> 6;
    const int wr   = wv >> 1;
    const int wc   = wv & 1;

    // bijective XCD swizzle (NWG % 8 == 0)
    const int flat = blockIdx.x;
    const int s    = (flat & 7) * (NWG / 8) + (flat >> 3);
    const size_t gm = (size_t)(s >> 2) * 128;   // M-tile (1024 of them)
    const int    gn = (s & 3) * 128;            // N-tile (4 of them)

    const int srow = tid >> 2;          // 0..63
    const int skk  = (tid & 3) * 8;     // 0,8,16,24

    f4_t acc[4][4] = {};

    const int l15 = lane & 15;
    const int lk  = (lane >> 4) * 8;

    for (int k0 = 0; k0 < 512; k0 += 32) {
#pragma unroll
        for (int i = 0; i < 2; ++i) {
            const unsigned short* gb = B + (size_t)(gn + i * 64 + srow) * 512 + k0 + skk;
            __builtin_amdgcn_global_load_lds((gvoid_t*)gb, (lvoid_t*)&Bs[i * 2048 + wv * 512], 16, 0, 0);
            if constexpr (AF32) {
                const float* ga = (const float*)Ap + (gm + (size_t)(i * 64 + srow)) * 512 + k0 + skk;
                float4 a0 = *reinterpret_cast<const float4*>(ga);
                float4 a1 = *reinterpret_cast<const float4*>(ga + 4);
                u16x8 o;
                o[0] = f2bf(a0.x); o[1] = f2bf(a0.y); o[2] = f2bf(a0.z); o[3] = f2bf(a0.w);
                o[4] = f2bf(a1.x); o[5] = f2bf(a1.y); o[6] = f2bf(a1.z); o[7] = f2bf(a1.w);
                *reinterpret_cast<u16x8*>(&As[i * 2048 + tid * 8]) = o;
            } else {
                const unsigned short* ga = (const unsigned short*)Ap + (gm + (size_t)(i * 64 + srow)) * 512 + k0 + skk;
                __builtin_amdgcn_global_load_lds((gvoid_t*)ga, (lvoid_t*)&As[i * 2048 + wv * 512], 16, 0, 0);
            }
        }
        __syncthreads();   // drains vmcnt + lgkmcnt; staged tile visible

        bf8_t af[4], bfz[4];
#pragma unroll
        for (int m = 0; m < 4; ++m)
            af[m] = *reinterpret_cast<const bf8_t*>(&As[(wr * 64 + m * 16 + l15) * 32 + lk]);
#pragma unroll
        for (int n = 0; n < 4; ++n)
            bfz[n] = *reinterpret_cast<const bf8_t*>(&Bs[(wc * 64 + n * 16 + l15) * 32 + lk]);
#pragma unroll
        for (int m = 0; m < 4; ++m)
#pragma unroll
            for (int n = 0; n < 4; ++n)
                acc[m][n] = __builtin_amdgcn_mfma_f32_16x16x32_bf16(af[m], bfz[n], acc[m][n], 0, 0, 0);
        __syncthreads();
    }

    // C/D layout (HW-verified): col = lane&15, row = (lane>>4)*4 + reg
    const int crow0 = (lane >> 4) * 4;
#pragma unroll
    for (int m = 0; m < 4; ++m)
#pragma unroll
        for (int n = 0; n < 4; ++n) {
            const size_t row0 = gm + (size_t)(wr * 64 + m * 16 + crow0);
            const int    col  = gn + wc * 64 + n * 16 + l15;
#pragma unroll
            for (int r = 0; r < 4; ++r)
                C[(row0 + r) * 512 + col] = f2bf(acc[m][n][r]);
        }
}

// ------------- chunk-parallel scan, pass 1: per-chunk (A,B) summaries -------
// f_chunk(H) = max(A, B + w^CLEN * H)  for H >= 0.
__global__ __launch_bounds__(256)
void k_scan_p1(const unsigned short* __restrict__ q,   // [T][16384] bf16
               const float* __restrict__ w_hh,
               const float* __restrict__ b_ih,
               float* __restrict__ Asum,               // [NCH][16384]
               float* __restrict__ Bsum) {
    const int g = (blockIdx.x & 63) * 256 + threadIdx.x;  // chain id
    const int c = blockIdx.x >> 6;                        // chunk id
    const float w  = w_hh[g & 511];
    const float bs = b_ih[g & 511];
    const unsigned short* p = q + (size_t)c * CLEN * S_STRIDE + g;

    float A = 0.f, Bv = 0.f;
    float s0[8], s1[8];
#pragma unroll
    for (int j = 0; j < 8; ++j) s0[j] = bf2f(p[(size_t)j * S_STRIDE]);
#pragma unroll
    for (int j = 0; j < 8; ++j) s1[j] = bf2f(p[(size_t)(8 + j) * S_STRIDE]);

    for (int j0 = 0; j0 < CLEN; j0 += 16) {
#pragma unroll
        for (int j = 0; j < 8; ++j) {
            float qv = s0[j] + bs;
            A  = fmaxf(fmaf(w, A, qv), 0.f);
            Bv = fmaf(w, Bv, qv);
        }
        if (j0 + 16 < CLEN) {
#pragma unroll
            for (int j = 0; j < 8; ++j) s0[j] = bf2f(p[(size_t)(j0 + 16 + j) * S_STRIDE]);
        }
#pragma unroll
        for (int j = 0; j < 8; ++j) {
            float qv = s1[j] + bs;
            A  = fmaxf(fmaf(w, A, qv), 0.f);
            Bv = fmaf(w, Bv, qv);
        }
        if (j0 + 24 < CLEN) {
#pragma unroll
            for (int j = 0; j < 8; ++j) s1[j] = bf2f(p[(size_t)(j0 + 24 + j) * S_STRIDE]);
        }
    }
    Asum[(size_t)c * NCHAIN + g] = A;
    Bsum[(size_t)c * NCHAIN + g] = Bv;
}

// ------------- pass 2: per-block stitch + exact replay ----------------------
// Each block recomputes its chunk's H_in from the (A,B) summaries (<=31
// dependent steps); c == NCH-1 blocks write hT after the replay.
// MODE 0: write f32 out; MODE 1: write bf16 (feeds next layer's GEMM)
template <int MODE>
__global__ __launch_bounds__(256)
void k_scan_p2(const unsigned short* __restrict__ q,
               const float* __restrict__ w_hh,
               const float* __restrict__ b_ih,
               const float* __restrict__ Asum,
               const float* __restrict__ Bsum,
               float* __restrict__ of32,
               unsigned short* __restrict__ ob16,
               float* __restrict__ hT) {
    const int g = (blockIdx.x & 63) * 256 + threadIdx.x;
    const int c = blockIdx.x >> 6;
    const float w  = w_hh[g & 511];
    const float bs = b_ih[g & 511];

    // stitch: H_in for chunk c (w^CLEN, CLEN = 2^7)
    float cw = w;
#pragma unroll
    for (int i = 0; i < 7; ++i) cw *= cw;
    float h = 0.f;
    for (int cc = 0; cc < c; ++cc)    // uniform trip count per block
        h = fmaxf(Asum[(size_t)cc * NCHAIN + g], fmaf(cw, h, Bsum[(size_t)cc * NCHAIN + g]));

    const size_t base = (size_t)c * CLEN * S_STRIDE + g;
    const unsigned short* p = q + base;

    float s0[8], s1[8];
#pragma unroll
    for (int j = 0; j < 8; ++j) s0[j] = bf2f(p[(size_t)j * S_STRIDE]);
#pragma unroll
    for (int j = 0; j < 8; ++j) s1[j] = bf2f(p[(size_t)(8 + j) * S_STRIDE]);

    for (int j0 = 0; j0 < CLEN; j0 += 16) {
#pragma unroll
        for (int j = 0; j < 8; ++j) {
            h = fmaxf(fmaf(w, h, s0[j] + bs), 0.f);
            const size_t idx = base + (size_t)(j0 + j) * S_STRIDE;
            if (MODE == 0) of32[idx] = h; else ob16[idx] = f2bf(h);
        }
        if (j0 + 16 < CLEN) {
#pragma unroll
            for (int j = 0; j < 8; ++j) s0[j] = bf2f(p[(size_t)(j0 + 16 + j) * S_STRIDE]);
        }
#pragma unroll
        for (int j = 0; j < 8; ++j) {
            h = fmaxf(fmaf(w, h, s1[j] + bs), 0.f);
            const size_t idx = base + (size_t)(j0 + 8 + j) * S_STRIDE;
            if (MODE == 0) of32[idx] = h; else ob16[idx] = f2bf(h);
        }
        if (j0 + 24 < CLEN) {
#pragma unroll
            for (int j = 0; j < 8; ++j) s1[j] = bf2f(p[(size_t)(j0 + 24 + j) * S_STRIDE]);
        }
    }
    if (c == NCH - 1) hT[g] = h;
}

extern "C" void kernel_launch(void* const* d_in, const int* in_sizes, int n_in,
                              void* d_out, int out_size, void* d_ws, size_t ws_size,
                              hipStream_t stream) {
    const float* x    = (const float*)d_in[0];   // (4096,32,512)
    const float* W_ih = (const float*)d_in[1];   // (2,512,512)
    const float* w_hh = (const float*)d_in[2];   // (2,512)
    const float* b_ih = (const float*)d_in[3];   // (2,512)

    // ---- workspace layout (~139 MB) ----
    unsigned short* proj2 = (unsigned short*)d_ws;                // 134 MB
    unsigned short* Wb    = proj2 + OUT_ELEMS;                    // 1 MB
    float* Asum = (float*)(Wb + 2 * 512 * 512);                   // 2 MB
    float* Bsum = Asum + (size_t)NCH * NCHAIN;                    // 2 MB

    // ---- d_out staging: proj1 (bf16) lower half, ys1 (bf16) upper half ----
    unsigned short* proj1 = (unsigned short*)d_out;
    unsigned short* ys1   = proj1 + OUT_ELEMS;
    float* out = (float*)d_out;
    float* hT  = out + OUT_ELEMS;                                 // h_n (2,32,512)

    const int sgrid = 64 * NCH;             // 2048 blocks for scan passes

    // 1. W -> bf16
    k_cvt<<<524288 / 8 / 256, 256, 0, stream>>>(W_ih, Wb);
    // 2. layer-0 GEMM (A = x f32, fused cvt) -> proj1
    k_gemm_bt<1><<<NWG, 256, 0, stream>>>(x, Wb, proj1);
    // 3-4. layer-0 chunked scan -> ys1 (bf16) + hT0
    k_scan_p1<<<sgrid, 256, 0, stream>>>(proj1, w_hh, b_ih, Asum, Bsum);
    k_scan_p2<1><<<sgrid, 256, 0, stream>>>(proj1, w_hh, b_ih, Asum, Bsum,
                                            nullptr, ys1, hT);
    // 5. layer-1 GEMM (A = ys1 bf16) -> proj2 (ws)
    k_gemm_bt<0><<<NWG, 256, 0, stream>>>(ys1, Wb + 512 * 512, proj2);
    // 6-7. layer-1 chunked scan -> final out (f32, overwrites proj1/ys1) + hT1
    k_scan_p1<<<sgrid, 256, 0, stream>>>(proj2, w_hh + DIM, b_ih + DIM, Asum, Bsum);
    k_scan_p2<0><<<sgrid, 256, 0, stream>>>(proj2, w_hh + DIM, b_ih + DIM, Asum, Bsum,
                                            out, nullptr, hT + NCHAIN);
}